// Round 4
// baseline (268.958 us; speedup 1.0000x reference)
//
#include <hip/hip_runtime.h>
#include <hip/hip_bf16.h>

// Static config: B=32, H=96, Wd=96, C=64, nW=4, K=3, WS=48, pool=16
#define NPIX 9216   // 96*96

typedef __attribute__((ext_vector_type(8))) short short8v;   // 8 bf16 (4 VGPRs)
typedef __attribute__((ext_vector_type(4))) float floatx4;   // 4 fp32

__device__ __forceinline__ float geluf(float x){
  return 0.5f * x * (1.0f + erff(x * 0.70710678118654752440f));
}
__device__ __forceinline__ float sigm(float x){
  return 1.0f / (1.0f + expf(-x));
}
__device__ __forceinline__ unsigned short f2bf(float f){
  __hip_bfloat16 h = __float2bfloat16(f);
  return *(unsigned short*)&h;
}

// ---------------------------------------------------------------------------
// Kernel A: windowed 48x48 -> 3x3 avg pool.  kern[bw=b*4+w][c][ki*3+kj]
// grid = 128 * 9 = 1152 blocks, 256 threads   (unchanged from round 3)
// ---------------------------------------------------------------------------
__global__ __launch_bounds__(256) void k_pool(const float* __restrict__ x,
                                              float* __restrict__ kern)
{
  int blk = blockIdx.x;
  int bw = blk / 9, rem = blk % 9;          // rem = ki*3+kj
  int ki = rem / 3, kj = rem % 3;
  int b = bw >> 2, w = bw & 3;
  int wr = w >> 1, wc = w & 1;
  int t = threadIdx.x;
  int cg = t & 15, rw = t >> 4;             // cg: 4-channel group, rw: row 0..15
  int h = wr*48 + ki*16 + rw;
  int col0 = wc*48 + kj*16;
  size_t base = ((size_t)(b*NPIX + h*96 + col0))*64 + cg*4;
  float a0=0.f,a1=0.f,a2=0.f,a3=0.f;
  #pragma unroll
  for (int j=0;j<16;j++){
    float4 u = *(const float4*)(x + base + (size_t)j*64);
    a0 += u.x; a1 += u.y; a2 += u.z; a3 += u.w;
  }
  __shared__ float red[16*64];
  float* rr = &red[rw*64 + cg*4];
  rr[0]=a0; rr[1]=a1; rr[2]=a2; rr[3]=a3;
  __syncthreads();
  if (t < 64){
    float s = 0.f;
    #pragma unroll
    for (int r=0;r<16;r++) s += red[r*64 + t];
    kern[(size_t)bw*576 + t*9 + rem] = s * (1.0f/256.0f);
  }
}

// ---------------------------------------------------------------------------
// Kernel B (rewritten): entire small graph per batch element.
// Layout discipline: lanes = output channel (stride-1 LDS), k-dim = wave-uniform
// broadcast; all big weights staged coalesced; fc1/fc2 via shuffle reduce.
// grid = 32 blocks, 256 threads
// ---------------------------------------------------------------------------
__global__ __launch_bounds__(256) void k_small(const float* __restrict__ kern_ws,
    const float* __restrict__ se_w1, const float* __restrict__ se_b1,
    const float* __restrict__ se_w2, const float* __restrict__ se_b2,
    const float* __restrict__ dc_w,  const float* __restrict__ dc_b,
    const float* __restrict__ l1_w,  const float* __restrict__ l1_b,
    const float* __restrict__ l2_w,  const float* __restrict__ l2_b,
    const float* __restrict__ gkf_w, const float* __restrict__ gkf_b,
    const float* __restrict__ fu_proj_w, const float* __restrict__ fu_proj_b,
    const float* __restrict__ fu_fc1_w,  const float* __restrict__ fu_fc1_b,
    const float* __restrict__ fu_fc2_w,  const float* __restrict__ fu_fc2_b,
    const float* __restrict__ fu_po_w,   const float* __restrict__ fu_po_b,
    const float* __restrict__ po_w,
    float* __restrict__ kc_ws,
    unsigned short* __restrict__ frag_pw)
{
  int b = blockIdx.x;
  int t = threadIdx.x;
  int lane = t & 63, wv = t >> 6;

  __shared__ float s_kern[4*64*12];  // [w][i][p] pad-12 (16B-aligned rows)
  __shared__ float s_t2[4*64*12];    // SE1 out, same layout
  __shared__ float s_w[64*65];       // staged transposed weights [i][o] pad-65
  __shared__ float s_kse[2304];      // [w][c][p] tight
  __shared__ float s_feats[2304];    // [g][o][p]  (= m*9+p, m=g*4+o)
  __shared__ float s_gkf[576];       // [c][p]
  __shared__ float s_xsum[576];      // [i][p]
  __shared__ float s_wwc[256];       // [w][c]
  __shared__ float s_v0[256];
  __shared__ float s_av[256];        // [w][c]
  __shared__ float s_v1[64];
  __shared__ float s_small[64];      // ww1(0..3), h1(16..31), ww2(32..35)

  // block 0: po_w as bf16 MFMA B-fragments (for k_conv)
  if (b == 0){
    for (int idx=t; idx<4096; idx+=256){
      int f = idx >> 9, L = (idx >> 3) & 63, j = idx & 7;
      int nb = f >> 1, kb = f & 1;
      int o = nb*16 + (L & 15);
      int c = kb*32 + ((L >> 4) & 3)*8 + j;
      frag_pw[idx] = f2bf(po_w[o*64 + c]);
    }
  }

  // P0: load kern (pad-12) + stage se_w1 transposed
  for (int idx=t; idx<2304; idx+=256){
    int w = idx/576, rem = idx%576, c = rem/9, p = rem%9;
    s_kern[(w*64+c)*12 + p] = kern_ws[b*2304 + idx];
  }
  for (int j=t; j<4096; j+=256){ int o=j>>6, i=j&63; s_w[i*65+o] = se_w1[j]; }
  __syncthreads();

  // P1: SE1  gelu(W1 @ kern + b1) -> s_t2[w][o][p]
  {
    float bo = se_b1[lane];
    float a0=bo,a1=bo,a2=bo,a3=bo,a4=bo,a5=bo,a6=bo,a7=bo,a8=bo;
    #pragma unroll 8
    for (int i=0;i<64;i++){
      float wvv = s_w[i*65 + lane];
      const float* kr = &s_kern[(wv*64+i)*12];
      float4 kA = *(const float4*)kr;
      float4 kB = *(const float4*)(kr+4);
      float kC = kr[8];
      a0 += wvv*kA.x; a1 += wvv*kA.y; a2 += wvv*kA.z; a3 += wvv*kA.w;
      a4 += wvv*kB.x; a5 += wvv*kB.y; a6 += wvv*kB.z; a7 += wvv*kB.w;
      a8 += wvv*kC;
    }
    float* dst = &s_t2[(wv*64+lane)*12];
    dst[0]=geluf(a0); dst[1]=geluf(a1); dst[2]=geluf(a2); dst[3]=geluf(a3);
    dst[4]=geluf(a4); dst[5]=geluf(a5); dst[6]=geluf(a6); dst[7]=geluf(a7);
    dst[8]=geluf(a8);
  }
  __syncthreads();

  // P2: stage se_w2
  for (int j=t; j<4096; j+=256){ int o=j>>6, i=j&63; s_w[i*65+o] = se_w2[j]; }
  __syncthreads();

  // P3: SE2 sigmoid -> s_kse[w][c][p];  also wwc (GAP of kern)
  {
    float bo = se_b2[lane];
    float a0=bo,a1=bo,a2=bo,a3=bo,a4=bo,a5=bo,a6=bo,a7=bo,a8=bo;
    #pragma unroll 8
    for (int i=0;i<64;i++){
      float wvv = s_w[i*65 + lane];
      const float* kr = &s_t2[(wv*64+i)*12];
      float4 kA = *(const float4*)kr;
      float4 kB = *(const float4*)(kr+4);
      float kC = kr[8];
      a0 += wvv*kA.x; a1 += wvv*kA.y; a2 += wvv*kA.z; a3 += wvv*kA.w;
      a4 += wvv*kB.x; a5 += wvv*kB.y; a6 += wvv*kB.z; a7 += wvv*kB.w;
      a8 += wvv*kC;
    }
    float* dst = &s_kse[wv*576 + lane*9];
    dst[0]=sigm(a0); dst[1]=sigm(a1); dst[2]=sigm(a2); dst[3]=sigm(a3);
    dst[4]=sigm(a4); dst[5]=sigm(a5); dst[6]=sigm(a6); dst[7]=sigm(a7);
    dst[8]=sigm(a8);
    // GAP over p of kern
    const float* kr = &s_kern[(wv*64+lane)*12];
    float s = kr[0]+kr[1]+kr[2]+kr[3]+kr[4]+kr[5]+kr[6]+kr[7]+kr[8];
    s_wwc[wv*64+lane] = s * (1.0f/9.0f);
  }
  __syncthreads();

  // P4: dc -> l1 -> l2 (tiny chain)
  if (t<4){ float acc = dc_b[t];
    for (int c=0;c<64;c++) acc += dc_w[t*64+c]*s_wwc[t*64+c];
    s_small[t]=acc; }
  __syncthreads();
  if (t<16){ float acc = l1_b[t];
    #pragma unroll
    for (int w=0;w<4;w++) acc += l1_w[t*4+w]*s_small[w];
    s_small[16+t]=geluf(acc); }
  __syncthreads();
  if (t<4){ float acc = l2_b[t];
    #pragma unroll
    for (int j=0;j<16;j++) acc += l2_w[t*16+j]*s_small[16+j];
    s_small[32+t]=sigm(acc); }
  __syncthreads();

  // P5: gkf[c][p] + stage proj_w (independent, same phase)
  for (int j=t; j<1024; j+=256){              // s_w[g*17+o*4+i] = proj_w[g][o][i]
    int g = j>>4, oi = j&15;
    s_w[g*17 + oi] = fu_proj_w[j];
  }
  for (int idx=t; idx<576; idx+=256){
    int c = idx & 63, p = idx >> 6;           // p in 0..8 (576=64*9)
    float acc = gkf_b[c];
    #pragma unroll
    for (int w=0;w<4;w++) acc += gkf_w[c*4+w]*s_kse[w*576+c*9+p]*s_small[32+w];
    s_gkf[c*9+p] = acc;
  }
  __syncthreads();

  // P6: feats[g][o][p] = gelu(proj_b + proj_w @ kse-group)
  for (int idx=t; idx<2304; idx+=256){
    int g = idx & 63, op = idx >> 6;          // op in 0..35
    int o = op / 9, p = op % 9;
    float acc = fu_proj_b[g*4+o];
    #pragma unroll
    for (int i=0;i<4;i++){
      int ch = g*4+i;
      acc += s_w[g*17 + o*4 + i] * s_kse[(ch>>6)*576 + (ch&63)*9 + p];
    }
    s_feats[(g*4+o)*9 + p] = geluf(acc);
  }
  __syncthreads();

  // P7: v0[m] = mean_p feats
  { float s=0.f;
    #pragma unroll
    for (int p=0;p<9;p++) s += s_feats[t*9+p];
    s_v0[t] = s*(1.0f/9.0f); }
  __syncthreads();

  // P8: fc1 (64 outputs, K=256) — coalesced loads + shuffle reduce
  {
    #pragma unroll
    for (int oi=0; oi<16; oi++){
      int o = wv*16 + oi;
      float v = 0.f;
      #pragma unroll
      for (int kb=0; kb<4; kb++)
        v += fu_fc1_w[o*256 + kb*64 + lane] * s_v0[kb*64 + lane];
      #pragma unroll
      for (int m=32; m>0; m>>=1) v += __shfl_xor(v, m);
      if (lane == 0) s_v1[o] = geluf(v + fu_fc1_b[o]);
    }
  }
  __syncthreads();

  // P9: fc2 (256 outputs, K=64) — coalesced loads + shuffle reduce
  {
    for (int mi=0; mi<64; mi++){
      int m = wv*64 + mi;
      float v = fu_fc2_w[m*64 + lane] * s_v1[lane];
      #pragma unroll
      for (int mm=32; mm>0; mm>>=1) v += __shfl_xor(v, mm);
      if (lane == 0) s_av[m] = v + fu_fc2_b[m];
    }
  }
  __syncthreads();

  // P10: softmax over w (per c)
  if (t<64){
    float z0=s_av[t], z1=s_av[64+t], z2=s_av[128+t], z3=s_av[192+t];
    float mx = fmaxf(fmaxf(z0,z1),fmaxf(z2,z3));
    float e0=expf(z0-mx), e1=expf(z1-mx), e2=expf(z2-mx), e3=expf(z3-mx);
    float inv = 1.0f/(e0+e1+e2+e3);
    s_av[t]=e0*inv; s_av[64+t]=e1*inv; s_av[128+t]=e2*inv; s_av[192+t]=e3*inv;
  }
  __syncthreads();

  // P11: xsum[i][p] + stage fu_po_w transposed (independent)
  for (int j=t; j<4096; j+=256){ int c=j>>6, i=j&63; s_w[i*65+c] = fu_po_w[j]; }
  for (int idx=t; idx<576; idx+=256){
    int c = idx & 63, p = idx >> 6;
    float s=0.f;
    #pragma unroll
    for (int w=0;w<4;w++) s += s_kse[w*576+c*9+p]*s_av[w*64+c];
    s_xsum[c*9+p]=s;
  }
  __syncthreads();

  // P12: kc[c][p] = 2*gkf + fu_po_w @ xsum + fu_po_b
  for (int idx=t; idx<576; idx+=256){
    int c = idx & 63, p = idx >> 6;
    float acc = 2.0f*s_gkf[c*9+p] + fu_po_b[c];
    #pragma unroll 8
    for (int i=0;i<64;i++) acc += s_w[i*65+c]*s_xsum[i*9+p];
    kc_ws[b*576 + c*9 + p] = acc;
  }
}

// ---------------------------------------------------------------------------
// Kernel C: depthwise 3x3 + MFMA 64x64x64 conv1x1   (unchanged from round 3)
// ---------------------------------------------------------------------------
__global__ __launch_bounds__(256, 4) void k_conv(const float* __restrict__ x,
                                                 const float* __restrict__ kc_ws,
                                                 const unsigned short* __restrict__ frag_pw,
                                                 const float* __restrict__ po_b,
                                                 float* __restrict__ out)
{
  int bi = blockIdx.x;
  int b = bi / 144, tile = bi % 144;
  int th = tile / 12, tw = tile % 12;
  int h0 = th*8, w0 = tw*8;
  int t = threadIdx.x;

  __shared__ float s_x[100*64];              // halo tile [r*10+col][c]
  __shared__ unsigned short s_tmp[64*72];    // depthwise result bf16, [px][c] stride 72
  __shared__ float s_kc[576];                // [c][p]

  for (int idx=t; idx<1600; idx+=256){
    int pix = idx >> 4, c4 = idx & 15;
    int r = pix / 10, col = pix % 10;
    int hh = h0 - 1 + r, ww = w0 - 1 + col;
    float4 v = make_float4(0.f,0.f,0.f,0.f);
    if (hh >= 0 && hh < 96 && ww >= 0 && ww < 96)
      v = *(const float4*)(x + (((size_t)b*NPIX + hh*96 + ww)<<6) + c4*4);
    *(float4*)&s_x[pix*64 + c4*4] = v;
  }
  for (int idx=t; idx<576; idx+=256) s_kc[idx] = kc_ws[b*576 + idx];
  __syncthreads();

  {
    int c = t & 63, rg = t >> 6;
    int r0 = rg*2;
    float k0=s_kc[c*9+0],k1=s_kc[c*9+1],k2=s_kc[c*9+2],
          k3=s_kc[c*9+3],k4=s_kc[c*9+4],k5=s_kc[c*9+5],
          k6=s_kc[c*9+6],k7=s_kc[c*9+7],k8=s_kc[c*9+8];
    float row[4][10];
    #pragma unroll
    for (int rr=0; rr<4; rr++)
      #pragma unroll
      for (int cc=0; cc<10; cc++)
        row[rr][cc] = s_x[((r0+rr)*10 + cc)*64 + c];
    #pragma unroll
    for (int dr=0; dr<2; dr++){
      int pr = r0 + dr;
      #pragma unroll
      for (int pc=0; pc<8; pc++){
        float acc = k0*row[dr+0][pc] + k1*row[dr+0][pc+1] + k2*row[dr+0][pc+2]
                  + k3*row[dr+1][pc] + k4*row[dr+1][pc+1] + k5*row[dr+1][pc+2]
                  + k6*row[dr+2][pc] + k7*row[dr+2][pc+1] + k8*row[dr+2][pc+2];
        s_tmp[(pr*8 + pc)*72 + c] = f2bf(acc);
      }
    }
  }
  __syncthreads();

  {
    int wv = t >> 6, lane = t & 63;
    int m = wv*16 + (lane & 15);
    int quad = lane >> 4;
    floatx4 acc[4] = {{0.f,0.f,0.f,0.f},{0.f,0.f,0.f,0.f},
                      {0.f,0.f,0.f,0.f},{0.f,0.f,0.f,0.f}};
    #pragma unroll
    for (int kb=0; kb<2; kb++){
      short8v afrag = *(const short8v*)&s_tmp[m*72 + kb*32 + quad*8];
      #pragma unroll
      for (int nb=0; nb<4; nb++){
        short8v bfrag = *(const short8v*)(frag_pw + (nb*2+kb)*512 + lane*8);
        acc[nb] = __builtin_amdgcn_mfma_f32_16x16x32_bf16(afrag, bfrag, acc[nb], 0, 0, 0);
      }
    }
    #pragma unroll
    for (int nb=0; nb<4; nb++){
      int o = nb*16 + (lane & 15);
      float pb = po_b[o];
      #pragma unroll
      for (int r=0; r<4; r++){
        int px = wv*16 + quad*4 + r;
        int hh = h0 + (px >> 3), wwp = w0 + (px & 7);
        out[(((size_t)b*NPIX + hh*96 + wwp)<<6) + o] = acc[nb][r] + pb;
      }
    }
  }
}

// ---------------------------------------------------------------------------
extern "C" void kernel_launch(void* const* d_in, const int* in_sizes, int n_in,
                              void* d_out, int out_size, void* d_ws, size_t ws_size,
                              hipStream_t stream) {
  const float* x        = (const float*)d_in[0];
  const float* se_w1    = (const float*)d_in[1];
  const float* se_b1    = (const float*)d_in[2];
  const float* se_w2    = (const float*)d_in[3];
  const float* se_b2    = (const float*)d_in[4];
  const float* dc_w     = (const float*)d_in[5];
  const float* dc_b     = (const float*)d_in[6];
  const float* l1_w     = (const float*)d_in[7];
  const float* l1_b     = (const float*)d_in[8];
  const float* l2_w     = (const float*)d_in[9];
  const float* l2_b     = (const float*)d_in[10];
  const float* gkf_w    = (const float*)d_in[11];
  const float* gkf_b    = (const float*)d_in[12];
  const float* fu_proj_w= (const float*)d_in[13];
  const float* fu_proj_b= (const float*)d_in[14];
  const float* fu_fc1_w = (const float*)d_in[15];
  const float* fu_fc1_b = (const float*)d_in[16];
  const float* fu_fc2_w = (const float*)d_in[17];
  const float* fu_fc2_b = (const float*)d_in[18];
  const float* fu_po_w  = (const float*)d_in[19];
  const float* fu_po_b  = (const float*)d_in[20];
  const float* po_w     = (const float*)d_in[21];
  const float* po_b     = (const float*)d_in[22];

  float* kern_ws = (float*)d_ws;                       // 128*576 floats
  float* kc_ws   = kern_ws + 73728;                    // 32*576 floats
  unsigned short* frag_pw = (unsigned short*)(kc_ws + 18432);  // 4096 ushort

  k_pool<<<1152, 256, 0, stream>>>(x, kern_ws);
  k_small<<<32, 256, 0, stream>>>(kern_ws, se_w1, se_b1, se_w2, se_b2,
                                  dc_w, dc_b, l1_w, l1_b, l2_w, l2_b,
                                  gkf_w, gkf_b, fu_proj_w, fu_proj_b,
                                  fu_fc1_w, fu_fc1_b, fu_fc2_w, fu_fc2_b,
                                  fu_po_w, fu_po_b, po_w, kc_ws, frag_pw);
  k_conv<<<4608, 256, 0, stream>>>(x, kc_ws, frag_pw, po_b, (float*)d_out);
}

// Round 5
// 233.806 us; speedup vs baseline: 1.1503x; 1.1503x over previous
//
#include <hip/hip_runtime.h>
#include <hip/hip_bf16.h>

// Static config: B=32, H=96, Wd=96, C=64, nW=4, K=3, WS=48, pool=16
#define NPIX 9216   // 96*96

typedef __attribute__((ext_vector_type(8))) short short8v;   // 8 bf16 (4 VGPRs)
typedef __attribute__((ext_vector_type(4))) float floatx4;   // 4 fp32

__device__ __forceinline__ float geluf(float x){
  return 0.5f * x * (1.0f + erff(x * 0.70710678118654752440f));
}
__device__ __forceinline__ float sigm(float x){
  return 1.0f / (1.0f + expf(-x));
}
__device__ __forceinline__ unsigned short f2bf(float f){
  __hip_bfloat16 h = __float2bfloat16(f);
  return *(unsigned short*)&h;
}

// ---------------------------------------------------------------------------
// Kernel A: windowed 48x48 -> 3x3 avg pool.  kern[bw=b*4+w][c][ki*3+kj]
// grid = 128 * 9 = 1152 blocks, 256 threads   (unchanged)
// ---------------------------------------------------------------------------
__global__ __launch_bounds__(256) void k_pool(const float* __restrict__ x,
                                              float* __restrict__ kern)
{
  int blk = blockIdx.x;
  int bw = blk / 9, rem = blk % 9;          // rem = ki*3+kj
  int ki = rem / 3, kj = rem % 3;
  int b = bw >> 2, w = bw & 3;
  int wr = w >> 1, wc = w & 1;
  int t = threadIdx.x;
  int cg = t & 15, rw = t >> 4;
  int h = wr*48 + ki*16 + rw;
  int col0 = wc*48 + kj*16;
  size_t base = ((size_t)(b*NPIX + h*96 + col0))*64 + cg*4;
  float a0=0.f,a1=0.f,a2=0.f,a3=0.f;
  #pragma unroll
  for (int j=0;j<16;j++){
    float4 u = *(const float4*)(x + base + (size_t)j*64);
    a0 += u.x; a1 += u.y; a2 += u.z; a3 += u.w;
  }
  __shared__ float red[16*64];
  float* rr = &red[rw*64 + cg*4];
  rr[0]=a0; rr[1]=a1; rr[2]=a2; rr[3]=a3;
  __syncthreads();
  if (t < 64){
    float s = 0.f;
    #pragma unroll
    for (int r=0;r<16;r++) s += red[r*64 + t];
    kern[(size_t)bw*576 + t*9 + rem] = s * (1.0f/256.0f);
  }
}

// ---------------------------------------------------------------------------
// Kernel B1: SE block per (b,w) window — 128 blocks, 256 threads.
// kse_ws[bw][c][p] = sigmoid(W2 @ gelu(W1 @ kern + b1) + b2)
// wwc_ws[bw][c]    = mean_p kern
// Block 0 also emits po_w MFMA B-fragments for k_conv.
// ---------------------------------------------------------------------------
__global__ __launch_bounds__(256) void k_se(const float* __restrict__ kern_ws,
    const float* __restrict__ se_w1, const float* __restrict__ se_b1,
    const float* __restrict__ se_w2, const float* __restrict__ se_b2,
    const float* __restrict__ po_w,
    float* __restrict__ kse_ws, float* __restrict__ wwc_ws,
    unsigned short* __restrict__ frag_pw)
{
  int bw = blockIdx.x;
  int t = threadIdx.x;
  __shared__ float s_w1[64*65];    // [i][o] pad-65, conflict-free lane reads
  __shared__ float s_w2[64*65];
  __shared__ float s_kern[64*13];  // [c][p] pad-13 (coprime w/ 32)
  __shared__ float s_t2[64*13];

  if (bw == 0){
    for (int idx=t; idx<4096; idx+=256){
      int f = idx >> 9, L = (idx >> 3) & 63, j = idx & 7;
      int nb = f >> 1, kb = f & 1;
      int o = nb*16 + (L & 15);
      int c = kb*32 + ((L >> 4) & 3)*8 + j;
      frag_pw[idx] = f2bf(po_w[o*64 + c]);
    }
  }
  // stage everything up-front (all loads in flight before the barrier)
  for (int idx=t; idx<576; idx+=256){
    int c = idx/9, p = idx%9;
    s_kern[c*13+p] = kern_ws[bw*576 + idx];
  }
  for (int j=t; j<4096; j+=256){
    int o=j>>6, i=j&63;
    s_w1[i*65+o] = se_w1[j];
    s_w2[i*65+o] = se_w2[j];
  }
  __syncthreads();
  // SE1: o = lane (conflict-free weight reads), p wave-uniform (broadcast)
  for (int idx=t; idx<576; idx+=256){
    int o = idx & 63, p = idx >> 6;
    float acc = se_b1[o];
    #pragma unroll 8
    for (int i=0;i<64;i++) acc += s_w1[i*65+o]*s_kern[i*13+p];
    s_t2[o*13+p] = geluf(acc);
  }
  __syncthreads();
  // SE2
  for (int idx=t; idx<576; idx+=256){
    int o = idx & 63, p = idx >> 6;
    float acc = se_b2[o];
    #pragma unroll 8
    for (int i=0;i<64;i++) acc += s_w2[i*65+o]*s_t2[i*13+p];
    kse_ws[bw*576 + o*9 + p] = sigm(acc);
  }
  if (t < 64){
    const float* kr = &s_kern[t*13];
    float s = kr[0]+kr[1]+kr[2]+kr[3]+kr[4]+kr[5]+kr[6]+kr[7]+kr[8];
    wwc_ws[bw*64 + t] = s * (1.0f/9.0f);
  }
}

// ---------------------------------------------------------------------------
// Kernel B2: rest of the small graph per batch element — 32 blocks, 256 thr.
// 8 short phases; every global-load loop unrolled (single latency each).
// ---------------------------------------------------------------------------
__global__ __launch_bounds__(256) void k_rest(const float* __restrict__ kse_ws,
    const float* __restrict__ wwc_ws,
    const float* __restrict__ dc_w,  const float* __restrict__ dc_b,
    const float* __restrict__ l1_w,  const float* __restrict__ l1_b,
    const float* __restrict__ l2_w,  const float* __restrict__ l2_b,
    const float* __restrict__ gkf_w, const float* __restrict__ gkf_b,
    const float* __restrict__ fu_proj_w, const float* __restrict__ fu_proj_b,
    const float* __restrict__ fu_fc1_w,  const float* __restrict__ fu_fc1_b,
    const float* __restrict__ fu_fc2_w,  const float* __restrict__ fu_fc2_b,
    const float* __restrict__ fu_po_w,   const float* __restrict__ fu_po_b,
    float* __restrict__ kc_ws)
{
  int b = blockIdx.x;
  int t = threadIdx.x;
  int lane = t & 63, wv = t >> 6;

  __shared__ float s_kse[2304];    // [w][c][p]
  __shared__ float s_wwc[256];     // [w][c]
  __shared__ float s_pow[64*65];   // fu_po_w transposed [i][c] pad-65
  __shared__ float s_prj[1088];    // proj_w [g*17 + o*4 + i]
  __shared__ float s_feats[2304];  // [m][p], m = g*4+o
  __shared__ float s_gkf[576];     // [c][p]
  __shared__ float s_xsum[576];    // [i][p]
  __shared__ float s_v0[256];
  __shared__ float s_av[256];      // [w][c]
  __shared__ float s_v1[64];
  __shared__ float s_small[64];    // ww1(0..3), h1(16..31), ww2(32..35)

  // P0: stage everything (coalesced, all in flight together)
  for (int idx=t; idx<2304; idx+=256) s_kse[idx] = kse_ws[b*2304 + idx];
  s_wwc[t] = wwc_ws[b*256 + t];
  for (int j=t; j<4096; j+=256){ int c=j>>6, i=j&63; s_pow[i*65+c] = fu_po_w[j]; }
  for (int j=t; j<1024; j+=256){ int g=j>>4, oi=j&15; s_prj[g*17+oi] = fu_proj_w[j]; }
  __syncthreads();

  // P1: feats (grouped proj + gelu)  ||  dc (lanes 0-3)
  for (int idx=t; idx<2304; idx+=256){
    int g = idx & 63, op = idx >> 6;
    int o = op / 9, p = op % 9;
    float acc = fu_proj_b[g*4+o];
    #pragma unroll
    for (int i=0;i<4;i++){
      int ch = g*4+i;
      acc += s_prj[g*17 + o*4 + i] * s_kse[(ch>>6)*576 + (ch&63)*9 + p];
    }
    s_feats[(g*4+o)*9 + p] = geluf(acc);
  }
  if (t<4){
    float acc = dc_b[t];
    #pragma unroll 8
    for (int c=0;c<64;c++) acc += dc_w[t*64+c]*s_wwc[t*64+c];
    s_small[t] = acc;
  }
  __syncthreads();

  // P2: v0 (GAP of feats)  ||  l1 (lanes 0-15)
  {
    const float* f = &s_feats[t*9];
    s_v0[t] = (f[0]+f[1]+f[2]+f[3]+f[4]+f[5]+f[6]+f[7]+f[8]) * (1.0f/9.0f);
  }
  if (t<16){
    float acc = l1_b[t];
    #pragma unroll
    for (int w=0;w<4;w++) acc += l1_w[t*4+w]*s_small[w];
    s_small[16+t] = geluf(acc);
  }
  __syncthreads();

  // P3: fc1 — 16 unrolled rows/wave, coalesced loads, shuffle reduce  ||  l2
  if (t<4){
    float acc = l2_b[t];
    #pragma unroll
    for (int j=0;j<16;j++) acc += l2_w[t*16+j]*s_small[16+j];
    s_small[32+t] = sigm(acc);
  }
  {
    #pragma unroll
    for (int oi=0; oi<16; oi++){
      int o = wv*16 + oi;
      float v = fu_fc1_w[o*256 +       lane] * s_v0[      lane]
              + fu_fc1_w[o*256 +  64 + lane] * s_v0[ 64 + lane]
              + fu_fc1_w[o*256 + 128 + lane] * s_v0[128 + lane]
              + fu_fc1_w[o*256 + 192 + lane] * s_v0[192 + lane];
      #pragma unroll
      for (int m=32; m>0; m>>=1) v += __shfl_xor(v, m);
      if (lane == 0) s_v1[o] = geluf(v + fu_fc1_b[o]);
    }
  }
  __syncthreads();

  // P4: fc2 — per-thread register dot (16 float4 loads, one latency) || gkf
  {
    const float4* wr = (const float4*)(fu_fc2_w + t*64);
    float acc = 0.f;
    #pragma unroll
    for (int q=0;q<16;q++){
      float4 wq = wr[q];
      acc += wq.x*s_v1[q*4] + wq.y*s_v1[q*4+1] + wq.z*s_v1[q*4+2] + wq.w*s_v1[q*4+3];
    }
    s_av[t] = acc + fu_fc2_b[t];
  }
  for (int idx=t; idx<576; idx+=256){
    int c = idx & 63, p = idx >> 6;
    float acc = gkf_b[c];
    #pragma unroll
    for (int w=0;w<4;w++) acc += gkf_w[c*4+w]*s_kse[w*576+c*9+p]*s_small[32+w];
    s_gkf[c*9+p] = acc;
  }
  __syncthreads();

  // P5: softmax over w per c
  if (t<64){
    float z0=s_av[t], z1=s_av[64+t], z2=s_av[128+t], z3=s_av[192+t];
    float mx = fmaxf(fmaxf(z0,z1),fmaxf(z2,z3));
    float e0=expf(z0-mx), e1=expf(z1-mx), e2=expf(z2-mx), e3=expf(z3-mx);
    float inv = 1.0f/(e0+e1+e2+e3);
    s_av[t]=e0*inv; s_av[64+t]=e1*inv; s_av[128+t]=e2*inv; s_av[192+t]=e3*inv;
  }
  __syncthreads();

  // P6: xsum[i][p]
  for (int idx=t; idx<576; idx+=256){
    int c = idx & 63, p = idx >> 6;
    float s=0.f;
    #pragma unroll
    for (int w=0;w<4;w++) s += s_kse[w*576+c*9+p]*s_av[w*64+c];
    s_xsum[c*9+p] = s;
  }
  __syncthreads();

  // P7: kc[c][p] = 2*gkf + fu_po_w @ xsum + fu_po_b
  for (int idx=t; idx<576; idx+=256){
    int c = idx & 63, p = idx >> 6;
    float acc = 2.0f*s_gkf[c*9+p] + fu_po_b[c];
    #pragma unroll 8
    for (int i=0;i<64;i++) acc += s_pow[i*65+c]*s_xsum[i*9+p];
    kc_ws[b*576 + c*9 + p] = acc;
  }
}

// ---------------------------------------------------------------------------
// Kernel C: depthwise 3x3 + MFMA 64x64x64 conv1x1   (unchanged)
// ---------------------------------------------------------------------------
__global__ __launch_bounds__(256, 4) void k_conv(const float* __restrict__ x,
                                                 const float* __restrict__ kc_ws,
                                                 const unsigned short* __restrict__ frag_pw,
                                                 const float* __restrict__ po_b,
                                                 float* __restrict__ out)
{
  int bi = blockIdx.x;
  int b = bi / 144, tile = bi % 144;
  int th = tile / 12, tw = tile % 12;
  int h0 = th*8, w0 = tw*8;
  int t = threadIdx.x;

  __shared__ float s_x[100*64];              // halo tile [r*10+col][c]
  __shared__ unsigned short s_tmp[64*72];    // depthwise result bf16, [px][c] stride 72
  __shared__ float s_kc[576];                // [c][p]

  for (int idx=t; idx<1600; idx+=256){
    int pix = idx >> 4, c4 = idx & 15;
    int r = pix / 10, col = pix % 10;
    int hh = h0 - 1 + r, ww = w0 - 1 + col;
    float4 v = make_float4(0.f,0.f,0.f,0.f);
    if (hh >= 0 && hh < 96 && ww >= 0 && ww < 96)
      v = *(const float4*)(x + (((size_t)b*NPIX + hh*96 + ww)<<6) + c4*4);
    *(float4*)&s_x[pix*64 + c4*4] = v;
  }
  for (int idx=t; idx<576; idx+=256) s_kc[idx] = kc_ws[b*576 + idx];
  __syncthreads();

  {
    int c = t & 63, rg = t >> 6;
    int r0 = rg*2;
    float k0=s_kc[c*9+0],k1=s_kc[c*9+1],k2=s_kc[c*9+2],
          k3=s_kc[c*9+3],k4=s_kc[c*9+4],k5=s_kc[c*9+5],
          k6=s_kc[c*9+6],k7=s_kc[c*9+7],k8=s_kc[c*9+8];
    float row[4][10];
    #pragma unroll
    for (int rr=0; rr<4; rr++)
      #pragma unroll
      for (int cc=0; cc<10; cc++)
        row[rr][cc] = s_x[((r0+rr)*10 + cc)*64 + c];
    #pragma unroll
    for (int dr=0; dr<2; dr++){
      int pr = r0 + dr;
      #pragma unroll
      for (int pc=0; pc<8; pc++){
        float acc = k0*row[dr+0][pc] + k1*row[dr+0][pc+1] + k2*row[dr+0][pc+2]
                  + k3*row[dr+1][pc] + k4*row[dr+1][pc+1] + k5*row[dr+1][pc+2]
                  + k6*row[dr+2][pc] + k7*row[dr+2][pc+1] + k8*row[dr+2][pc+2];
        s_tmp[(pr*8 + pc)*72 + c] = f2bf(acc);
      }
    }
  }
  __syncthreads();

  {
    int wv = t >> 6, lane = t & 63;
    int m = wv*16 + (lane & 15);
    int quad = lane >> 4;
    floatx4 acc[4] = {{0.f,0.f,0.f,0.f},{0.f,0.f,0.f,0.f},
                      {0.f,0.f,0.f,0.f},{0.f,0.f,0.f,0.f}};
    #pragma unroll
    for (int kb=0; kb<2; kb++){
      short8v afrag = *(const short8v*)&s_tmp[m*72 + kb*32 + quad*8];
      #pragma unroll
      for (int nb=0; nb<4; nb++){
        short8v bfrag = *(const short8v*)(frag_pw + (nb*2+kb)*512 + lane*8);
        acc[nb] = __builtin_amdgcn_mfma_f32_16x16x32_bf16(afrag, bfrag, acc[nb], 0, 0, 0);
      }
    }
    #pragma unroll
    for (int nb=0; nb<4; nb++){
      int o = nb*16 + (lane & 15);
      float pb = po_b[o];
      #pragma unroll
      for (int r=0; r<4; r++){
        int px = wv*16 + quad*4 + r;
        int hh = h0 + (px >> 3), wwp = w0 + (px & 7);
        out[(((size_t)b*NPIX + hh*96 + wwp)<<6) + o] = acc[nb][r] + pb;
      }
    }
  }
}

// ---------------------------------------------------------------------------
extern "C" void kernel_launch(void* const* d_in, const int* in_sizes, int n_in,
                              void* d_out, int out_size, void* d_ws, size_t ws_size,
                              hipStream_t stream) {
  const float* x        = (const float*)d_in[0];
  const float* se_w1    = (const float*)d_in[1];
  const float* se_b1    = (const float*)d_in[2];
  const float* se_w2    = (const float*)d_in[3];
  const float* se_b2    = (const float*)d_in[4];
  const float* dc_w     = (const float*)d_in[5];
  const float* dc_b     = (const float*)d_in[6];
  const float* l1_w     = (const float*)d_in[7];
  const float* l1_b     = (const float*)d_in[8];
  const float* l2_w     = (const float*)d_in[9];
  const float* l2_b     = (const float*)d_in[10];
  const float* gkf_w    = (const float*)d_in[11];
  const float* gkf_b    = (const float*)d_in[12];
  const float* fu_proj_w= (const float*)d_in[13];
  const float* fu_proj_b= (const float*)d_in[14];
  const float* fu_fc1_w = (const float*)d_in[15];
  const float* fu_fc1_b = (const float*)d_in[16];
  const float* fu_fc2_w = (const float*)d_in[17];
  const float* fu_fc2_b = (const float*)d_in[18];
  const float* fu_po_w  = (const float*)d_in[19];
  const float* fu_po_b  = (const float*)d_in[20];
  const float* po_w     = (const float*)d_in[21];
  const float* po_b     = (const float*)d_in[22];

  float* kern_ws = (float*)d_ws;                       // 128*576 = 73728 floats
  float* kc_ws   = kern_ws + 73728;                    // 32*576  = 18432 floats
  unsigned short* frag_pw = (unsigned short*)(kc_ws + 18432);   // 4096 ushort (2048 floats)
  float* kse_ws  = kc_ws + 18432 + 2048;               // 128*576 = 73728 floats
  float* wwc_ws  = kse_ws + 73728;                     // 128*64  = 8192 floats

  k_pool<<<1152, 256, 0, stream>>>(x, kern_ws);
  k_se<<<128, 256, 0, stream>>>(kern_ws, se_w1, se_b1, se_w2, se_b2, po_w,
                                kse_ws, wwc_ws, frag_pw);
  k_rest<<<32, 256, 0, stream>>>(kse_ws, wwc_ws,
                                 dc_w, dc_b, l1_w, l1_b, l2_w, l2_b,
                                 gkf_w, gkf_b, fu_proj_w, fu_proj_b,
                                 fu_fc1_w, fu_fc1_b, fu_fc2_w, fu_fc2_b,
                                 fu_po_w, fu_po_b, kc_ws);
  k_conv<<<4608, 256, 0, stream>>>(x, kc_ws, frag_pw, po_b, (float*)d_out);
}